// Round 24
// baseline (259.772 us; speedup 1.0000x reference)
//
#include <hip/hip_runtime.h>
#include <hip/hip_bf16.h>

#define BATCH 32
#define SEQ   2048
#define EMB   1024
#define HS    64
#define BT    (BATCH*SEQ)   // 65536 rows

typedef short s16x4 __attribute__((ext_vector_type(4)));
typedef short s16x8 __attribute__((ext_vector_type(8)));
typedef float f32x4 __attribute__((ext_vector_type(4)));
using u16 = unsigned short;

static __device__ __forceinline__ short f2bf(float f) {
  __hip_bfloat16 h = __float2bfloat16(f);
  return *reinterpret_cast<short*>(&h);
}
static __device__ __forceinline__ void gl_lds16(const void* g, void* l) {
  __builtin_amdgcn_global_load_lds(
      (const __attribute__((address_space(1))) unsigned int*)g,
      (__attribute__((address_space(3))) unsigned int*)l, 16, 0, 0);
}

#define MFMA __builtin_amdgcn_mfma_f32_16x16x32_bf16

// ---------------------------------------------------------------------------
// W -> bf16, transposed: Wt[n][k], n = w*64+h (Wk|Wq|Wv). 768 KB once.
// ---------------------------------------------------------------------------
__global__ __launch_bounds__(256) void wconv_kernel(
    const float* __restrict__ Wk, const float* __restrict__ Wq,
    const float* __restrict__ Wv, short* __restrict__ Wt)
{
  const int n = blockIdx.x;            // 0..191
  const int w = n >> 6, h = n & 63;
  const float* Wp = (w == 0) ? Wk : (w == 1) ? Wq : Wv;
  const int k0 = threadIdx.x * 4;
  s16x4 p;
  #pragma unroll
  for (int e = 0; e < 4; ++e) p[e] = f2bf(Wp[(size_t)(k0 + e) * HS + h]);
  *(s16x4*)(Wt + (size_t)n * EMB + k0) = p;
}

// ---------------------------------------------------------------------------
// Projection v9: BARRIER-FREE via WAVE-PRIVATE LDS staging.
// All 7 prior variants kept cross-wave barriers per K-step -> phase-lock ->
// serial pipe-sum (74us = HBM 42.5 + MFMA 12 + LDS 12 + VALU 6). R22 showed
// global fragment-scatter is fatal, so staging stays -- but wave-PRIVATE:
// wave w owns rows w*16..+15 x all 192 cols; per K=32 chunk it stages its
// own 16x32 x slice into a private LDS strip (no __syncthreads anywhere;
// same-wave LDS RAW ordered by lgkmcnt). Register pipeline: chunk k+1's x
// loads issue before chunk k's MFMA block. All 4 waves load IDENTICAL Wt
// B-frag addresses -> L1 broadcast (L2 traffic /4). Waves drift freely ->
// HBM/MFMA/LDS pipes overlap across 16 waves/CU (m114 mechanism).
// acc[12]=48 + pipeline regs ~110 VGPR -> 4 blocks/CU; LDS 5 KB.
// ---------------------------------------------------------------------------
__global__ __launch_bounds__(256, 4) void proj_kernel(
    const float* __restrict__ x, const short* __restrict__ Wt,
    short* __restrict__ kb, short* __restrict__ qb, short* __restrict__ vt)
{
  __shared__ __align__(16) u16 xw[4][16][40];   // wave-private strips, pad-40
  const int tid = threadIdx.x;
  const int row0 = blockIdx.x * 64;
  const int w  = tid >> 6, l = tid & 63;
  const int lr = l & 15, lg = l >> 4;
  const int srow = l >> 2, scol = (l & 3) * 8;  // staging: 4 lanes/row, 32B each

  const float* xbase = x + (size_t)(row0 + w*16 + srow) * EMB + scol;

  f32x4 acc[12];
  #pragma unroll
  for (int n = 0; n < 12; ++n) acc[n] = f32x4{0.f, 0.f, 0.f, 0.f};

  // register pipeline: x chunk k+1 loaded while chunk k computes
  float4 xa = *(const float4*)(xbase);
  float4 xb = *(const float4*)(xbase + 4);

  #pragma unroll 1
  for (int k0 = 0; k0 < EMB; k0 += 32) {
    // cvt + private ds_write of THIS chunk
    s16x8 p;
    p[0]=f2bf(xa.x); p[1]=f2bf(xa.y); p[2]=f2bf(xa.z); p[3]=f2bf(xa.w);
    p[4]=f2bf(xb.x); p[5]=f2bf(xb.y); p[6]=f2bf(xb.z); p[7]=f2bf(xb.w);
    *(s16x8*)&xw[w][srow][scol] = p;
    // issue NEXT chunk's x loads (in flight through MFMA block below)
    if (k0 + 32 < EMB) {
      xa = *(const float4*)(xbase + k0 + 32);
      xb = *(const float4*)(xbase + k0 + 36);
    }
    // A-frag from private strip (same-wave RAW: lgkmcnt, no barrier)
    s16x8 a = *(const s16x8*)&xw[w][lr][lg*8];
    // 12 B-frags (identical addresses across waves -> L1 broadcast) + MFMA
    #pragma unroll
    for (int n = 0; n < 12; ++n) {
      s16x8 bw = *(const s16x8*)(Wt + (size_t)(n*16 + lr) * EMB + k0 + lg*8);
      acc[n] = MFMA(a, bw, acc[n], 0, 0, 0);
    }
  }

  // epilogue: wave w owns rows row0+w*16+lg*4+r, n-frag col h = n*16+lr
  const int b  = row0 >> 11;
  const int t0 = row0 & 2047;
  const int trow = w*16 + lg*4;
  #pragma unroll
  for (int n = 0; n < 12; ++n) {
    const int wm = n >> 2;                // 0=k,1=q,2=v (compile-time per n)
    const int h  = (n*16 + lr) & 63;
    if (wm == 2) {
      s16x4 pk;
      #pragma unroll
      for (int r = 0; r < 4; ++r) pk[r] = f2bf(acc[n][r]);
      *(s16x4*)(vt + ((size_t)(b*64 + h)) * SEQ + t0 + trow) = pk;
    } else {
      short* dst = (wm == 0) ? kb : qb;
      #pragma unroll
      for (int r = 0; r < 4; ++r)
        dst[(size_t)(row0 + trow + r) * HS + h] = f2bf(acc[n][r]);
    }
  }
}

// ---------------------------------------------------------------------------
// Flash attention v10 (R16/R20 form, verbatim -- best measured): dbuf q_s/v_s
// via global_load_lds (pre-swizzled global source), one barrier per tile,
// fixed-max softmax, ones-MFMA row-sum, LPT + XCD swizzle, 3 blocks/CU.
// ---------------------------------------------------------------------------
__global__ __launch_bounds__(256, 3) void attn_kernel(
    const short* __restrict__ kb, const short* __restrict__ qb,
    const short* __restrict__ vt, float* __restrict__ out)
{
  __shared__ __align__(16) u16 q_s[2][4096];
  __shared__ __align__(16) u16 v_s[2][4096];
  __shared__ __align__(16) u16 P_lds[4][16][72];   // per-wave private
  const int bid = blockIdx.x;
  const int wg  = (bid & 7) * 128 + (bid >> 3);    // 128 blocks (4 batches)/XCD
  const int b   = wg >> 5;
  const int it  = 31 - (wg & 31);                  // heavy i-tiles first (LPT)
  const int tid = threadIdx.x;
  const int w   = tid >> 6;                        // 0..3 (16-row strip)
  const int lr  = tid & 15;
  const int lg  = (tid & 63) >> 4;
  const int iw0 = it * 64 + w * 16;

  const short* qbb = qb + (size_t)b * SEQ * HS;
  const short* vtb = vt + (size_t)b * 64 * SEQ;

  const int srow0 = (0*256 + tid) >> 3, sc80 = tid & 7;
  const int srow1 = (256 + tid) >> 3;
  const int gcol0 = (sc80 * 8) ^ ((srow0 & 7) << 3);
  const int gcol1 = (sc80 * 8) ^ ((srow1 & 7) << 3);

#define STAGE(BUF, J0) do {                                                    \
    u16* lq0 = &q_s[BUF][(w*64) * 8];                                          \
    u16* lv0 = &v_s[BUF][(w*64) * 8];                                          \
    u16* lq1 = &q_s[BUF][(256 + w*64) * 8];                                    \
    u16* lv1 = &v_s[BUF][(256 + w*64) * 8];                                    \
    gl_lds16(qbb + (size_t)((J0) + srow0) * HS + gcol0, lq0);                  \
    gl_lds16(vtb + (size_t)srow0 * SEQ + (J0) + gcol0, lv0);                   \
    gl_lds16(qbb + (size_t)((J0) + srow1) * HS + gcol1, lq1);                  \
    gl_lds16(vtb + (size_t)srow1 * SEQ + (J0) + gcol1, lv1);                   \
  } while (0)

  s16x8 ones;
  #pragma unroll
  for (int e = 0; e < 8; ++e) ones[e] = (short)0x3F80;   // bf16 1.0

  s16x8 kfrag[2];
  {
    const short* kp = kb + ((size_t)(b*SEQ) + iw0 + lr) * HS + lg*8;
    kfrag[0] = *(const s16x8*)(kp);
    kfrag[1] = *(const s16x8*)(kp + 32);
  }

  f32x4 o[4];
  #pragma unroll
  for (int n = 0; n < 4; ++n) o[n] = f32x4{0.f, 0.f, 0.f, 0.f};
  f32x4 lac = f32x4{0.f, 0.f, 0.f, 0.f};

  STAGE(0, 0);
  __syncthreads();

  int cur = 0;
  #pragma unroll 1
  for (int jt = 0; jt <= it; ++jt) {
    if (jt < it) STAGE(cur ^ 1, (jt + 1) * 64);
    const u16* qsb = q_s[cur];
    const u16* vsb = v_s[cur];
    f32x4 sc[4];
    #pragma unroll
    for (int s = 0; s < 4; ++s) {
      const int row = s*16 + lr, base = row * 64, swz = (row & 7) << 3;
      s16x8 q0 = *(const s16x8*)&qsb[base + ((lg*8) ^ swz)];
      s16x8 q1 = *(const s16x8*)&qsb[base + ((32 + lg*8) ^ swz)];
      f32x4 z = f32x4{0.f, 0.f, 0.f, 0.f};
      z = MFMA(q0, kfrag[0], z, 0, 0, 0);
      z = MFMA(q1, kfrag[1], z, 0, 0, 0);
      sc[s] = z;
    }
    const bool diag = (jt == it);
    #pragma unroll
    for (int s = 0; s < 4; ++s) {
      s16x4 pk;
      #pragma unroll
      for (int r = 0; r < 4; ++r) {
        float e = __expf(fmaf(sc[s][r], 0.03125f, -4.0f));
        if (diag && (s*16 + lg*4 + r > w*16 + lr)) e = 0.f;
        pk[r] = f2bf(e);
      }
      *(s16x4*)&P_lds[w][lr][16*s + 4*lg] = pk;
    }
    s16x8 pA0 = *(const s16x8*)&P_lds[w][lr][8*lg];
    s16x8 pA1 = *(const s16x8*)&P_lds[w][lr][32 + 8*lg];
    __builtin_amdgcn_s_setprio(1);
    #pragma unroll
    for (int n = 0; n < 4; ++n) {
      const int rowh = n*16 + lr, base = rowh * 64, swz = (rowh & 7) << 3;
      s16x8 v0 = *(const s16x8*)&vsb[base + ((lg*8) ^ swz)];
      s16x8 v1 = *(const s16x8*)&vsb[base + ((32 + lg*8) ^ swz)];
      o[n] = MFMA(pA0, v0, o[n], 0, 0, 0);
      o[n] = MFMA(pA1, v1, o[n], 0, 0, 0);
    }
    lac = MFMA(pA0, ones, lac, 0, 0, 0);
    lac = MFMA(pA1, ones, lac, 0, 0, 0);
    __builtin_amdgcn_s_setprio(0);
    __syncthreads();
    cur ^= 1;
  }
#undef STAGE

  float inv[4];
  #pragma unroll
  for (int r = 0; r < 4; ++r) inv[r] = 1.f / lac[r];
  #pragma unroll
  for (int n = 0; n < 4; ++n)
    #pragma unroll
    for (int r = 0; r < 4; ++r)
      out[((size_t)(b*SEQ) + iw0 + lg*4 + r) * HS + n*16 + lr] = o[n][r] * inv[r];
}

extern "C" void kernel_launch(void* const* d_in, const int* in_sizes, int n_in,
                              void* d_out, int out_size, void* d_ws, size_t ws_size,
                              hipStream_t stream) {
  const float* x  = (const float*)d_in[0];
  const float* Wk = (const float*)d_in[1];
  const float* Wq = (const float*)d_in[2];
  const float* Wv = (const float*)d_in[3];
  float* out = (float*)d_out;
  const size_t PLANE = (size_t)BT * HS;          // 4M elements
  short* kb = (short*)d_ws;                      // bf16 [BT][64]
  short* qb = kb + PLANE;                        // bf16 [BT][64]
  short* vt = kb + 2*PLANE;                      // bf16 [B][64][SEQ]
  short* Wt = kb + 3*PLANE;                      // bf16 [192][1024]

  wconv_kernel<<<192, 256, 0, stream>>>(Wk, Wq, Wv, Wt);
  proj_kernel<<<BT/64, 256, 0, stream>>>(x, Wt, kb, qb, vt);
  attn_kernel<<<BATCH*(SEQ/64), 256, 0, stream>>>(kb, qb, vt, out);
}

// Round 25
// 126.030 us; speedup vs baseline: 2.0612x; 2.0612x over previous
//
#include <hip/hip_runtime.h>
#include <hip/hip_bf16.h>

#define BATCH 32
#define SEQ   2048
#define EMB   1024
#define HS    64
#define BT    (BATCH*SEQ)   // 65536 rows

typedef short s16x4 __attribute__((ext_vector_type(4)));
typedef short s16x8 __attribute__((ext_vector_type(8)));
typedef float f32x4 __attribute__((ext_vector_type(4)));
using u16 = unsigned short;

static __device__ __forceinline__ short f2bf(float f) {
  __hip_bfloat16 h = __float2bfloat16(f);
  return *reinterpret_cast<short*>(&h);
}
static __device__ __forceinline__ void gl_lds16(const void* g, void* l) {
  __builtin_amdgcn_global_load_lds(
      (const __attribute__((address_space(1))) unsigned int*)g,
      (__attribute__((address_space(3))) unsigned int*)l, 16, 0, 0);
}

#define MFMA __builtin_amdgcn_mfma_f32_16x16x32_bf16

// ---------------------------------------------------------------------------
// W -> bf16, transposed: Wt[n][k], n = w*64+h (Wk|Wq|Wv). 768 KB once.
// ---------------------------------------------------------------------------
__global__ __launch_bounds__(256) void wconv_kernel(
    const float* __restrict__ Wk, const float* __restrict__ Wq,
    const float* __restrict__ Wv, short* __restrict__ Wt)
{
  const int n = blockIdx.x;            // 0..191
  const int w = n >> 6, h = n & 63;
  const float* Wp = (w == 0) ? Wk : (w == 1) ? Wq : Wv;
  const int k0 = threadIdx.x * 4;
  s16x4 p;
  #pragma unroll
  for (int e = 0; e < 4; ++e) p[e] = f2bf(Wp[(size_t)(k0 + e) * HS + h]);
  *(s16x4*)(Wt + (size_t)n * EMB + k0) = p;
}

// ---------------------------------------------------------------------------
// Projection (R20 form -- best of 8 measured variants, 74us). 64x192 tile,
// BK=64, col-split waves, x staged via LDS (coalesced), W direct from L2,
// per-block K-phase rotation. Structural floor: serial pipe-sum of the
// 2-phase barrier loop (HBM 42.5 + MFMA 12 + LDS 12 + VALU 6); reg-prefetch,
// LDS-dbuf, gl_lds-dbuf, producer-consumer, and two barrier-free forms all
// regressed (global fragment loads scatter 16 rows -> TA request floor).
// ---------------------------------------------------------------------------
__global__ __launch_bounds__(256, 4) void proj_kernel(
    const float* __restrict__ x, const short* __restrict__ Wt,
    short* __restrict__ kb, short* __restrict__ qb, short* __restrict__ vt)
{
  __shared__ __align__(16) u16 xs[64][72];
  const int tid  = threadIdx.x;
  const int row0 = blockIdx.x * 64;
  const int w  = tid >> 6, l = tid & 63;
  const int lr = l & 15, lg = l >> 4;
  const int kphase = (blockIdx.x & 3) << 8;   // 0,256,512,768

  f32x4 acc[4][3];
  #pragma unroll
  for (int m = 0; m < 4; ++m)
    #pragma unroll
    for (int n = 0; n < 3; ++n) acc[m][n] = f32x4{0.f, 0.f, 0.f, 0.f};

  for (int ks = 0; ks < EMB; ks += 64) {
    const int k0 = (ks + kphase) & (EMB - 1);
    s16x8 bw[2][3];
    #pragma unroll
    for (int kk = 0; kk < 2; ++kk)
      #pragma unroll
      for (int n = 0; n < 3; ++n)
        bw[kk][n] = *(const s16x8*)(Wt + (size_t)(w*48 + n*16 + lr) * EMB + k0 + kk*32 + lg*8);
    __syncthreads();
    #pragma unroll
    for (int i = 0; i < 4; ++i) {
      const int idx = i * 256 + tid;
      const int r = idx >> 4, c4 = idx & 15;
      float4 t = *(const float4*)(x + (size_t)(row0 + r) * EMB + k0 + c4 * 4);
      s16x4 p;
      p[0] = f2bf(t.x); p[1] = f2bf(t.y); p[2] = f2bf(t.z); p[3] = f2bf(t.w);
      *(s16x4*)&xs[r][c4 * 4] = p;
    }
    __syncthreads();
    #pragma unroll
    for (int kk = 0; kk < 2; ++kk) {
      s16x8 a[4];
      #pragma unroll
      for (int m = 0; m < 4; ++m)
        a[m] = *(const s16x8*)&xs[m*16 + lr][kk*32 + lg*8];
      #pragma unroll
      for (int m = 0; m < 4; ++m)
        #pragma unroll
        for (int n = 0; n < 3; ++n)
          acc[m][n] = MFMA(a[m], bw[kk][n], acc[m][n], 0, 0, 0);
    }
  }

  const int b  = row0 >> 11;
  const int t0 = row0 & 2047;
  #pragma unroll
  for (int m = 0; m < 4; ++m) {
    const int trow = m*16 + lg*4;
    #pragma unroll
    for (int n = 0; n < 3; ++n) {
      const int nbase = w*48 + n*16;
      const int wm = nbase >> 6;
      const int h  = (nbase + lr) & 63;
      if (wm == 2) {
        s16x4 p;
        #pragma unroll
        for (int r = 0; r < 4; ++r) p[r] = f2bf(acc[m][n][r]);
        *(s16x4*)(vt + ((size_t)(b*64 + h)) * SEQ + t0 + trow) = p;
      } else {
        short* dst = (wm == 0) ? kb : qb;
        #pragma unroll
        for (int r = 0; r < 4; ++r)
          dst[(size_t)(row0 + trow + r) * HS + h] = f2bf(acc[m][n][r]);
      }
    }
  }
}

// ---------------------------------------------------------------------------
// Flash attention v10 (R16/R20 form -- best measured): dbuf q_s/v_s via
// global_load_lds (pre-swizzled global source), one barrier per tile,
// fixed-max softmax, ones-MFMA row-sum, LPT + XCD swizzle, 3 blocks/CU.
// ---------------------------------------------------------------------------
__global__ __launch_bounds__(256, 3) void attn_kernel(
    const short* __restrict__ kb, const short* __restrict__ qb,
    const short* __restrict__ vt, float* __restrict__ out)
{
  __shared__ __align__(16) u16 q_s[2][4096];
  __shared__ __align__(16) u16 v_s[2][4096];
  __shared__ __align__(16) u16 P_lds[4][16][72];   // per-wave private
  const int bid = blockIdx.x;
  const int wg  = (bid & 7) * 128 + (bid >> 3);    // 128 blocks (4 batches)/XCD
  const int b   = wg >> 5;
  const int it  = 31 - (wg & 31);                  // heavy i-tiles first (LPT)
  const int tid = threadIdx.x;
  const int w   = tid >> 6;                        // 0..3 (16-row strip)
  const int lr  = tid & 15;
  const int lg  = (tid & 63) >> 4;
  const int iw0 = it * 64 + w * 16;

  const short* qbb = qb + (size_t)b * SEQ * HS;
  const short* vtb = vt + (size_t)b * 64 * SEQ;

  const int srow0 = (0*256 + tid) >> 3, sc80 = tid & 7;
  const int srow1 = (256 + tid) >> 3;
  const int gcol0 = (sc80 * 8) ^ ((srow0 & 7) << 3);
  const int gcol1 = (sc80 * 8) ^ ((srow1 & 7) << 3);

#define STAGE(BUF, J0) do {                                                    \
    u16* lq0 = &q_s[BUF][(w*64) * 8];                                          \
    u16* lv0 = &v_s[BUF][(w*64) * 8];                                          \
    u16* lq1 = &q_s[BUF][(256 + w*64) * 8];                                    \
    u16* lv1 = &v_s[BUF][(256 + w*64) * 8];                                    \
    gl_lds16(qbb + (size_t)((J0) + srow0) * HS + gcol0, lq0);                  \
    gl_lds16(vtb + (size_t)srow0 * SEQ + (J0) + gcol0, lv0);                   \
    gl_lds16(qbb + (size_t)((J0) + srow1) * HS + gcol1, lq1);                  \
    gl_lds16(vtb + (size_t)srow1 * SEQ + (J0) + gcol1, lv1);                   \
  } while (0)

  s16x8 ones;
  #pragma unroll
  for (int e = 0; e < 8; ++e) ones[e] = (short)0x3F80;   // bf16 1.0

  s16x8 kfrag[2];
  {
    const short* kp = kb + ((size_t)(b*SEQ) + iw0 + lr) * HS + lg*8;
    kfrag[0] = *(const s16x8*)(kp);
    kfrag[1] = *(const s16x8*)(kp + 32);
  }

  f32x4 o[4];
  #pragma unroll
  for (int n = 0; n < 4; ++n) o[n] = f32x4{0.f, 0.f, 0.f, 0.f};
  f32x4 lac = f32x4{0.f, 0.f, 0.f, 0.f};

  STAGE(0, 0);
  __syncthreads();

  int cur = 0;
  #pragma unroll 1
  for (int jt = 0; jt <= it; ++jt) {
    if (jt < it) STAGE(cur ^ 1, (jt + 1) * 64);
    const u16* qsb = q_s[cur];
    const u16* vsb = v_s[cur];
    f32x4 sc[4];
    #pragma unroll
    for (int s = 0; s < 4; ++s) {
      const int row = s*16 + lr, base = row * 64, swz = (row & 7) << 3;
      s16x8 q0 = *(const s16x8*)&qsb[base + ((lg*8) ^ swz)];
      s16x8 q1 = *(const s16x8*)&qsb[base + ((32 + lg*8) ^ swz)];
      f32x4 z = f32x4{0.f, 0.f, 0.f, 0.f};
      z = MFMA(q0, kfrag[0], z, 0, 0, 0);
      z = MFMA(q1, kfrag[1], z, 0, 0, 0);
      sc[s] = z;
    }
    const bool diag = (jt == it);
    #pragma unroll
    for (int s = 0; s < 4; ++s) {
      s16x4 pk;
      #pragma unroll
      for (int r = 0; r < 4; ++r) {
        float e = __expf(fmaf(sc[s][r], 0.03125f, -4.0f));
        if (diag && (s*16 + lg*4 + r > w*16 + lr)) e = 0.f;
        pk[r] = f2bf(e);
      }
      *(s16x4*)&P_lds[w][lr][16*s + 4*lg] = pk;
    }
    s16x8 pA0 = *(const s16x8*)&P_lds[w][lr][8*lg];
    s16x8 pA1 = *(const s16x8*)&P_lds[w][lr][32 + 8*lg];
    __builtin_amdgcn_s_setprio(1);
    #pragma unroll
    for (int n = 0; n < 4; ++n) {
      const int rowh = n*16 + lr, base = rowh * 64, swz = (rowh & 7) << 3;
      s16x8 v0 = *(const s16x8*)&vsb[base + ((lg*8) ^ swz)];
      s16x8 v1 = *(const s16x8*)&vsb[base + ((32 + lg*8) ^ swz)];
      o[n] = MFMA(pA0, v0, o[n], 0, 0, 0);
      o[n] = MFMA(pA1, v1, o[n], 0, 0, 0);
    }
    lac = MFMA(pA0, ones, lac, 0, 0, 0);
    lac = MFMA(pA1, ones, lac, 0, 0, 0);
    __builtin_amdgcn_s_setprio(0);
    __syncthreads();
    cur ^= 1;
  }
#undef STAGE

  float inv[4];
  #pragma unroll
  for (int r = 0; r < 4; ++r) inv[r] = 1.f / lac[r];
  #pragma unroll
  for (int n = 0; n < 4; ++n)
    #pragma unroll
    for (int r = 0; r < 4; ++r)
      out[((size_t)(b*SEQ) + iw0 + lg*4 + r) * HS + n*16 + lr] = o[n][r] * inv[r];
}

extern "C" void kernel_launch(void* const* d_in, const int* in_sizes, int n_in,
                              void* d_out, int out_size, void* d_ws, size_t ws_size,
                              hipStream_t stream) {
  const float* x  = (const float*)d_in[0];
  const float* Wk = (const float*)d_in[1];
  const float* Wq = (const float*)d_in[2];
  const float* Wv = (const float*)d_in[3];
  float* out = (float*)d_out;
  const size_t PLANE = (size_t)BT * HS;          // 4M elements
  short* kb = (short*)d_ws;                      // bf16 [BT][64]
  short* qb = kb + PLANE;                        // bf16 [BT][64]
  short* vt = kb + 2*PLANE;                      // bf16 [B][64][SEQ]
  short* Wt = kb + 3*PLANE;                      // bf16 [192][1024]

  wconv_kernel<<<192, 256, 0, stream>>>(Wk, Wq, Wv, Wt);
  proj_kernel<<<BT/64, 256, 0, stream>>>(x, Wt, kb, qb, vt);
  attn_kernel<<<BATCH*(SEQ/64), 256, 0, stream>>>(kb, qb, vt, out);
}